// Round 7
// baseline (1011.910 us; speedup 1.0000x reference)
//
#include <hip/hip_runtime.h>
#include <cstdint>

// Problem: B=4, N=1024, C=768, H=12, hd=64
// Outputs fp32 concat: out[4,1024,768] then attn[4,12,1024,1024]
#define OUT0_ELEMS 3145728   // 4096*768
#define QKV_F32    3145728   // 48*1024*64 elements per tensor

// ---------------------------------------------------------------------------
// Tiled fp32 GEMM: C[M][O] = A[M][768] @ W[O][768]^T + bias
// BM=BN=128, BK=16, 256 threads, 8x8 micro-tile, XOR-swizzled LDS columns.
// DOUBLE-BUFFERED: next-tile global loads issue before the compute of the
// current tile, so ~2048 FMA cycles cover the load latency (was exposed).
// SCATTER=1: qkv epilogue -> Q(*0.125)[n][d] / KT[d][n] / V[n][d] layouts.
// SCATTER=0: plain C0[m][o] write (proj).
// ---------------------------------------------------------------------------
template<int SCATTER>
__global__ __launch_bounds__(256)
void gemm128(const float* __restrict__ A, const float* __restrict__ W,
             const float* __restrict__ bias,
             float* __restrict__ C0, float* __restrict__ C1, float* __restrict__ C2)
{
    __shared__ float As[2][16][132];   // col-swizzled: col c at c ^ ((c&32)>>3)
    __shared__ float Ws[2][16][132];
    const int tid = threadIdx.x;
    const int tx = tid & 15;            // col group (8 cols)
    const int ty = tid >> 4;            // row group (8 rows)
    const int m0 = blockIdx.y * 128;
    const int o0 = blockIdx.x * 128;
    const int lr = tid >> 2;            // 0..63 (staging row)
    const int lk = (tid & 3) << 2;      // 0,4,8,12 (staging k)

    const int cs0 = lr ^ ((lr & 32) >> 3);
    const int cs1 = cs0 + 64;

    const float* Ar0 = A + (size_t)(m0 + lr) * 768 + lk;
    const float* Ar1 = Ar0 + (size_t)64 * 768;
    const float* Wr0 = W + (size_t)(o0 + lr) * 768 + lk;
    const float* Wr1 = Wr0 + (size_t)64 * 768;

    const int ab = ty << 3;
    const int ax = (ab & 32) >> 3;
    const int a0i = ab ^ ax, a1i = (ab + 4) ^ ax;
    const int bb = tx << 3;
    const int bx = (bb & 32) >> 3;
    const int b0i = bb ^ bx, b1i = (bb + 4) ^ bx;

    // prologue: stage tile 0 into buffer 0
    {
        float4 av0 = *(const float4*)(Ar0);
        float4 av1 = *(const float4*)(Ar1);
        float4 wv0 = *(const float4*)(Wr0);
        float4 wv1 = *(const float4*)(Wr1);
        As[0][lk+0][cs0]=av0.x; As[0][lk+1][cs0]=av0.y; As[0][lk+2][cs0]=av0.z; As[0][lk+3][cs0]=av0.w;
        As[0][lk+0][cs1]=av1.x; As[0][lk+1][cs1]=av1.y; As[0][lk+2][cs1]=av1.z; As[0][lk+3][cs1]=av1.w;
        Ws[0][lk+0][cs0]=wv0.x; Ws[0][lk+1][cs0]=wv0.y; Ws[0][lk+2][cs0]=wv0.z; Ws[0][lk+3][cs0]=wv0.w;
        Ws[0][lk+0][cs1]=wv1.x; Ws[0][lk+1][cs1]=wv1.y; Ws[0][lk+2][cs1]=wv1.z; Ws[0][lk+3][cs1]=wv1.w;
    }
    __syncthreads();

    float acc[8][8] = {};
    int cur = 0;

    for (int k0 = 16; k0 <= 768; k0 += 16) {
        const bool more = (k0 < 768);
        float4 av0, av1, wv0, wv1;
        if (more) {                         // issue next-tile loads FIRST
            av0 = *(const float4*)(Ar0 + k0);
            av1 = *(const float4*)(Ar1 + k0);
            wv0 = *(const float4*)(Wr0 + k0);
            wv1 = *(const float4*)(Wr1 + k0);
        }
        #pragma unroll
        for (int kk = 0; kk < 16; ++kk) {   // compute current buffer
            float4 aL = *(const float4*)&As[cur][kk][a0i];
            float4 aH = *(const float4*)&As[cur][kk][a1i];
            float4 bL = *(const float4*)&Ws[cur][kk][b0i];
            float4 bH = *(const float4*)&Ws[cur][kk][b1i];
            float a[8] = {aL.x,aL.y,aL.z,aL.w,aH.x,aH.y,aH.z,aH.w};
            float b[8] = {bL.x,bL.y,bL.z,bL.w,bH.x,bH.y,bH.z,bH.w};
            #pragma unroll
            for (int i = 0; i < 8; ++i)
                #pragma unroll
                for (int j = 0; j < 8; ++j)
                    acc[i][j] = fmaf(a[i], b[j], acc[i][j]);
        }
        if (more) {
            __syncthreads();                // readers of other buffer done
            const int nb = cur ^ 1;
            As[nb][lk+0][cs0]=av0.x; As[nb][lk+1][cs0]=av0.y; As[nb][lk+2][cs0]=av0.z; As[nb][lk+3][cs0]=av0.w;
            As[nb][lk+0][cs1]=av1.x; As[nb][lk+1][cs1]=av1.y; As[nb][lk+2][cs1]=av1.z; As[nb][lk+3][cs1]=av1.w;
            Ws[nb][lk+0][cs0]=wv0.x; Ws[nb][lk+1][cs0]=wv0.y; Ws[nb][lk+2][cs0]=wv0.z; Ws[nb][lk+3][cs0]=wv0.w;
            Ws[nb][lk+0][cs1]=wv1.x; Ws[nb][lk+1][cs1]=wv1.y; Ws[nb][lk+2][cs1]=wv1.z; Ws[nb][lk+3][cs1]=wv1.w;
            __syncthreads();                // stores visible
            cur = nb;
        }
    }

    const float4 bj0 = *(const float4*)(bias + o0 + bb);
    const float4 bj1 = *(const float4*)(bias + o0 + bb + 4);

    if (SCATTER) {
        const int oc   = o0 + bb;
        const int sidx = oc / 768;
        const int rem  = oc - sidx * 768;
        const int h = rem >> 6, d0 = rem & 63;
        const int b = m0 >> 10;                     // 128 | 1024 => constant
        const int nbase = (m0 & 1023) + (ty << 3);
        if (sidx == 1) {
            // K^T: KT[bh][d][n]; 8 consecutive n per d row
            const float bjv[8] = {bj0.x,bj0.y,bj0.z,bj0.w,bj1.x,bj1.y,bj1.z,bj1.w};
            float* Tb = C1 + ((size_t)(b * 12 + h) << 16) + ((size_t)d0 << 10) + nbase;
            #pragma unroll
            for (int j = 0; j < 8; ++j) {
                const float bj = bjv[j];
                float4 r0 = {acc[0][j]+bj, acc[1][j]+bj, acc[2][j]+bj, acc[3][j]+bj};
                float4 r1 = {acc[4][j]+bj, acc[5][j]+bj, acc[6][j]+bj, acc[7][j]+bj};
                *(float4*)(Tb + ((size_t)j << 10))     = r0;
                *(float4*)(Tb + ((size_t)j << 10) + 4) = r1;
            }
        } else {
            const float scale = (sidx == 0) ? 0.125f : 1.0f;
            float* T = (sidx == 0) ? C0 : C2;
            float* Tb = T + ((size_t)(b * 12 + h) * 1024) * 64 + d0;
            #pragma unroll
            for (int i = 0; i < 8; ++i) {
                const int n = nbase + i;
                float4 r0, r1;
                r0.x=(acc[i][0]+bj0.x)*scale; r0.y=(acc[i][1]+bj0.y)*scale;
                r0.z=(acc[i][2]+bj0.z)*scale; r0.w=(acc[i][3]+bj0.w)*scale;
                r1.x=(acc[i][4]+bj1.x)*scale; r1.y=(acc[i][5]+bj1.y)*scale;
                r1.z=(acc[i][6]+bj1.z)*scale; r1.w=(acc[i][7]+bj1.w)*scale;
                *(float4*)(Tb + (size_t)n * 64)     = r0;
                *(float4*)(Tb + (size_t)n * 64 + 4) = r1;
            }
        }
    } else {
        #pragma unroll
        for (int i = 0; i < 8; ++i) {
            const int m = m0 + (ty << 3) + i;
            float4 r0, r1;
            r0.x=acc[i][0]+bj0.x; r0.y=acc[i][1]+bj0.y;
            r0.z=acc[i][2]+bj0.z; r0.w=acc[i][3]+bj0.w;
            r1.x=acc[i][4]+bj1.x; r1.y=acc[i][5]+bj1.y;
            r1.z=acc[i][6]+bj1.z; r1.w=acc[i][7]+bj1.w;
            *(float4*)(C0 + (size_t)m * 768 + o0 + bb)     = r0;
            *(float4*)(C0 + (size_t)m * 768 + o0 + bb + 4) = r1;
        }
    }
}

// ---------------------------------------------------------------------------
// Scores + softmax + row0 fix + attn write. 16 query rows per block.
// Phase 1 COALESCED via K^T[d][n]: each thread owns 4 CONSECUTIVE keys
// (4*tid..4*tid+3); one float4 load per d is a fully-coalesced wave read
// (1024 contiguous bytes). acc[16][4] (64 VGPR) — the 16q shape that the
// compiler handled without spilling/sinking (round-5 lesson: 8q got VGPR=60).
// Phases 2-4 are the proven round-4 code (softmax 16 lanes/row, (j+q)
// rotation = 2-way banks; serial row0 fix; coalesced write).
// grid = (64 row-tiles, 48 bh), 256 threads, 68 KB LDS (2 blocks/CU).
// ---------------------------------------------------------------------------
__global__ __launch_bounds__(256)
void attn_scores(const float* __restrict__ Q, const float* __restrict__ KT,
                 const float* __restrict__ cls_bias, float* __restrict__ attn)
{
    __shared__ float s[16 * 1024];   // 64 KB: 16 score rows
    __shared__ float qs[16 * 64];    // 4 KB: Q tile (pre-scaled by 0.125)
    const int tid = threadIdx.x;
    const int bh  = blockIdx.y;
    const int rt  = blockIdx.x;
    const int q0  = rt << 4;
    const size_t bhoff = (size_t)bh << 16;   // bh * 1024 * 64

    ((float4*)qs)[tid] = ((const float4*)(Q + bhoff + ((size_t)q0 << 6)))[tid];
    __syncthreads();

    // ---- phase 1: acc[q][j] = Q[q] . keys (4*tid+j), K^T coalesced ----
    {
        const float* KTb = KT + bhoff;       // [d][n]: d*1024 + n
        const int kb = tid << 2;             // 4 consecutive keys
        float acc[16][4] = {};
        float4 kf = *(const float4*)(KTb + kb);
        #pragma unroll 1
        for (int d = 0; d < 64; ++d) {
            const int dn = (d < 63) ? d + 1 : 63;            // clamped prefetch
            float4 kn = *(const float4*)(KTb + ((size_t)dn << 10) + kb);
            #pragma unroll
            for (int q = 0; q < 16; ++q) {
                const float qv = qs[(q << 6) + d];           // LDS broadcast
                acc[q][0] = fmaf(qv, kf.x, acc[q][0]);
                acc[q][1] = fmaf(qv, kf.y, acc[q][1]);
                acc[q][2] = fmaf(qv, kf.z, acc[q][2]);
                acc[q][3] = fmaf(qv, kf.w, acc[q][3]);
            }
            kf = kn;
        }
        #pragma unroll
        for (int q = 0; q < 16; ++q) {
            float4 r = {acc[q][0], acc[q][1], acc[q][2], acc[q][3]};
            *(float4*)&s[(q << 10) + kb] = r;
        }
    }
    __syncthreads();

    // ---- phase 2: softmax, 16 lanes per row; (j+q) rotation -> 2-way banks
    {
        const int q = tid >> 4, sub = tid & 15;
        float* row = s + (q << 10);
        float mx = -3.0e38f;
        #pragma unroll 4
        for (int j = 0; j < 64; ++j)
            mx = fmaxf(mx, row[sub + (((j + q) & 63) << 4)]);
        #pragma unroll
        for (int off = 8; off; off >>= 1) mx = fmaxf(mx, __shfl_xor(mx, off, 16));
        float sm = 0.f;
        #pragma unroll 4
        for (int j = 0; j < 64; ++j) {
            const int k = sub + (((j + q) & 63) << 4);
            const float e = __expf(row[k] - mx);
            row[k] = e;
            sm += e;
        }
        #pragma unroll
        for (int off = 8; off; off >>= 1) sm += __shfl_xor(sm, off, 16);
        const float inv = 1.0f / sm;
        #pragma unroll 4
        for (int j = 0; j < 64; ++j)
            row[sub + (((j + q) & 63) << 4)] *= inv;
    }

    // ---- row0 fix: global query 0; row 0 was normalized by these same
    // lanes (tid<16 belong to q-group 0), so no extra sync needed ----
    if (rt == 0 && tid < 16) {
        const float p0  = s[0];
        const float a00 = fminf(fmaxf(p0 + cls_bias[bh % 12], 0.f), 1.f);
        float actual = 0.f;
        for (int j = 0; j < 64; ++j) {
            const int k = tid + (j << 4);
            if (k) actual += s[k];
        }
        #pragma unroll
        for (int off = 8; off; off >>= 1) actual += __shfl_xor(actual, off, 16);
        const float mp = (1.0f - a00) / (actual + 1e-6f);
        for (int j = 0; j < 64; ++j) {
            const int k = tid + (j << 4);
            s[k] = (k == 0) ? a00 : fminf(fmaxf(s[k] * mp, 0.f), 1.f);
        }
    }
    __syncthreads();

    // ---- phase 3: write attn (output 1), coalesced float4 ----
    {
        float4* dst = (float4*)(attn + ((size_t)bh << 20) + ((size_t)q0 << 10));
        const float4* src = (const float4*)s;
        #pragma unroll
        for (int i = 0; i < 16; ++i)
            dst[tid + (i << 8)] = src[tid + (i << 8)];
    }
}

// ---------------------------------------------------------------------------
// O1 = attn @ V per (b,h): M=1024, K=1024, N=64. Tiled GEMM, 64x64 tile,
// Bk=16, 4x4 micro-tile, double-buffered LDS (loads overlap compute).
// grid = (16 m-tiles, 48 bh), 256 threads, ~17 KB LDS.
// ---------------------------------------------------------------------------
__global__ __launch_bounds__(256)
void pv_gemm(const float* __restrict__ attn, const float* __restrict__ V,
             float* __restrict__ O1)
{
    __shared__ float Pt[2][16][68];   // [buf][k][m], stride 272 B
    __shared__ float Vt[2][16][64];   // [buf][k][n]
    const int tid = threadIdx.x;
    const int bh  = blockIdx.y;
    const int m0  = blockIdx.x << 6;
    const int b   = bh / 12, h = bh - b * 12;
    const size_t bhoff = (size_t)bh << 16;
    const float* Pg = attn + ((size_t)bh << 20);

    const int pr = tid >> 2;            // 0..63  P stage row
    const int pk = (tid & 3) << 2;      // 0,4,8,12
    const int vk = tid >> 4;            // 0..15  V stage k
    const int vn = (tid & 15) << 2;     // n quad
    const int tx = tid & 15, ty = tid >> 4;

    // prologue: stage k0=0 into buffer 0
    {
        float4 pv4 = *(const float4*)(Pg + (size_t)(m0 + pr) * 1024 + pk);
        float4 vv4 = *(const float4*)(V + bhoff + (size_t)vk * 64 + vn);
        Pt[0][pk+0][pr] = pv4.x; Pt[0][pk+1][pr] = pv4.y;
        Pt[0][pk+2][pr] = pv4.z; Pt[0][pk+3][pr] = pv4.w;
        *(float4*)&Vt[0][vk][vn] = vv4;
    }
    __syncthreads();

    float acc[4][4] = {};
    int cur = 0;

    for (int k0 = 16; k0 <= 1024; k0 += 16) {
        const bool more = (k0 < 1024);
        float4 pv4, vv4;
        if (more) {
            pv4 = *(const float4*)(Pg + (size_t)(m0 + pr) * 1024 + k0 + pk);
            vv4 = *(const float4*)(V + bhoff + (size_t)(k0 + vk) * 64 + vn);
        }
        #pragma unroll
        for (int kk = 0; kk < 16; ++kk) {
            float4 a  = *(const float4*)&Pt[cur][kk][ty << 2];
            float4 bv = *(const float4*)&Vt[cur][kk][tx << 2];
            float av[4] = {a.x, a.y, a.z, a.w};
            float bb[4] = {bv.x, bv.y, bv.z, bv.w};
            #pragma unroll
            for (int i = 0; i < 4; ++i)
                #pragma unroll
                for (int j = 0; j < 4; ++j)
                    acc[i][j] = fmaf(av[i], bb[j], acc[i][j]);
        }
        if (more) {
            __syncthreads();
            const int nb = cur ^ 1;
            Pt[nb][pk+0][pr] = pv4.x; Pt[nb][pk+1][pr] = pv4.y;
            Pt[nb][pk+2][pr] = pv4.z; Pt[nb][pk+3][pr] = pv4.w;
            *(float4*)&Vt[nb][vk][vn] = vv4;
            __syncthreads();
            cur = nb;
        }
    }

    #pragma unroll
    for (int i = 0; i < 4; ++i) {
        float4 r = {acc[i][0], acc[i][1], acc[i][2], acc[i][3]};
        const int m = m0 + (ty << 2) + i;
        *(float4*)(O1 + ((size_t)(b * 1024 + m)) * 768 + (h << 6) + (tx << 2)) = r;
    }
}

extern "C" void kernel_launch(void* const* d_in, const int* in_sizes, int n_in,
                              void* d_out, int out_size, void* d_ws, size_t ws_size,
                              hipStream_t stream) {
    const float* x        = (const float*)d_in[0];
    const float* qkv_w    = (const float*)d_in[1];
    const float* qkv_b    = (const float*)d_in[2];
    const float* proj_w   = (const float*)d_in[3];
    const float* proj_b   = (const float*)d_in[4];
    const float* cls_bias = (const float*)d_in[5];

    float* out  = (float*)d_out;
    float* attn = out + OUT0_ELEMS;

    float* ws = (float*)d_ws;
    float* Q  = ws;                       // 12.6 MB (pre-scaled by 0.125), [bh][n][d]
    float* KT = Q  + (size_t)QKV_F32;     // 12.6 MB, [bh][d][n]  (transposed!)
    float* V  = KT + (size_t)QKV_F32;     // 12.6 MB, [bh][n][d]
    float* O1 = V  + (size_t)QKV_F32;     // 12.6 MB

    // 1) qkv = x @ qkv_w.T + qkv_b -> Q(scaled)/KT/V
    gemm128<1><<<dim3(18, 32), 256, 0, stream>>>(x, qkv_w, qkv_b, Q, KT, V);
    // 2) attn = row0-fixed softmax(Q K^T)  (output 1)
    attn_scores<<<dim3(64, 48), 256, 0, stream>>>(Q, KT, cls_bias, attn);
    // 3) O1 = attn @ V  (reads the just-written attn, L3-resident)
    pv_gemm<<<dim3(16, 48), 256, 0, stream>>>(attn, V, O1);
    // 4) out = O1 @ proj_w.T + proj_b  (output 0)
    gemm128<0><<<dim3(6, 32), 256, 0, stream>>>(O1, proj_w, proj_b, out, nullptr, nullptr);
}

// Round 8
// 676.421 us; speedup vs baseline: 1.4960x; 1.4960x over previous
//
#include <hip/hip_runtime.h>
#include <cstdint>

// Problem: B=4, N=1024, C=768, H=12, hd=64
// Outputs fp32 concat: out[4,1024,768] then attn[4,12,1024,1024]
#define OUT0_ELEMS 3145728   // 4096*768
#define QKV_F32    3145728   // 48*1024*64 elements per tensor

typedef __attribute__((ext_vector_type(8))) short bf16x8;   // 8 bf16 = 4 VGPR
typedef __attribute__((ext_vector_type(4))) float f32x4;    // MFMA C/D

// Truncating bf16 split: x ~= h + l with |x - h - l| <= 2^-16 |x|.
__device__ __forceinline__ void split_bf16(float x, unsigned short &h, unsigned short &l) {
    unsigned bx = __float_as_uint(x);
    h = (unsigned short)(bx >> 16);
    float fh = __uint_as_float(((unsigned)h) << 16);
    float r  = x - fh;
    l = (unsigned short)(__float_as_uint(r) >> 16);
}

// 8 consecutive floats (two float4) -> packed hi-chunk + lo-chunk (8 bf16 each).
__device__ __forceinline__ void pack8(const float4 &u, const float4 &v,
                                      uint4 &hp, uint4 &lp) {
    unsigned short h0,l0,h1,l1,h2,l2,h3,l3,h4,l4,h5,l5,h6,l6,h7,l7;
    split_bf16(u.x,h0,l0); split_bf16(u.y,h1,l1);
    split_bf16(u.z,h2,l2); split_bf16(u.w,h3,l3);
    split_bf16(v.x,h4,l4); split_bf16(v.y,h5,l5);
    split_bf16(v.z,h6,l6); split_bf16(v.w,h7,l7);
    hp = make_uint4((unsigned)h0 | ((unsigned)h1 << 16), (unsigned)h2 | ((unsigned)h3 << 16),
                    (unsigned)h4 | ((unsigned)h5 << 16), (unsigned)h6 | ((unsigned)h7 << 16));
    lp = make_uint4((unsigned)l0 | ((unsigned)l1 << 16), (unsigned)l2 | ((unsigned)l3 << 16),
                    (unsigned)l4 | ((unsigned)l5 << 16), (unsigned)l6 | ((unsigned)l7 << 16));
}

// ---------------------------------------------------------------------------
// MFMA GEMM via bf16 split: C[M][O] = A[M][768] @ W[O][768]^T + bias.
// BM=BN=128, BK=32, 256 threads = 4 waves (2x2), each wave 64x64 output
// = 4x4 mfma_f32_16x16x32_bf16 frags; 3 passes (hh, hl, lh) per k-step.
// LDS: Ah/Al/Wh/Wl 128x32 bf16 (8 KB each, 32 KB total), 16B-chunk XOR
// swizzle (chunk ^ ((row>>1)&3)) -> reads AND writes at the 8-dword/bank floor.
// K-dim frag mapping note: A and B frags use the SAME assumed k-layout
// (chunk g=lane>>4, 8 consecutive k), so any HW k-permutation cancels.
// SCATTER=1: qkv epilogue -> Q(*0.125)[n][d] / KT[d][n] / V[n][d].
// SCATTER=0: plain C0[m][o] (proj).
// ---------------------------------------------------------------------------
template<int SCATTER>
__global__ __launch_bounds__(256)
void gemm_mfma(const float* __restrict__ A, const float* __restrict__ W,
               const float* __restrict__ bias,
               float* __restrict__ C0, float* __restrict__ C1, float* __restrict__ C2)
{
    __shared__ __align__(16) unsigned short Ah[4096], Al[4096], Wh[4096], Wl[4096];
    const int tid = threadIdx.x;
    const int m0 = blockIdx.y * 128;
    const int o0 = blockIdx.x * 128;

    // staging: thread -> (row, k-half); two 8-bf16 chunks per tile
    const int srow  = tid >> 1;
    const int khalf = tid & 1;
    const int sswz  = (srow >> 1) & 3;
    const int wi0 = srow * 32 + (((khalf << 1)    ) ^ sswz) * 8;
    const int wi1 = srow * 32 + (((khalf << 1) | 1) ^ sswz) * 8;

    const float* Ar = A + (size_t)(m0 + srow) * 768 + khalf * 16;
    const float* Wr = W + (size_t)(o0 + srow) * 768 + khalf * 16;

    // wave/lane decomposition for MFMA fragments
    const int l   = tid & 63;
    const int wid = tid >> 6;
    const int wm  = wid >> 1, wn = wid & 1;
    const int fr  = l & 15;          // A-row / B-col within frag
    const int g   = l >> 4;          // k-chunk (8 bf16)
    int aidx[4], bidx[4];
    #pragma unroll
    for (int i = 0; i < 4; ++i) {
        const int ar = wm * 64 + i * 16 + fr;
        aidx[i] = ar * 32 + ((g ^ ((ar >> 1) & 3)) * 8);
        const int br = wn * 64 + i * 16 + fr;
        bidx[i] = br * 32 + ((g ^ ((br >> 1) & 3)) * 8);
    }

    const f32x4 zf = {0.f, 0.f, 0.f, 0.f};
    f32x4 acc[4][4];
    #pragma unroll
    for (int i = 0; i < 4; ++i)
        #pragma unroll
        for (int j = 0; j < 4; ++j) acc[i][j] = zf;

    // prologue: load k-step 0
    float4 a0 = *(const float4*)(Ar    ), a1 = *(const float4*)(Ar + 4);
    float4 a2 = *(const float4*)(Ar + 8), a3 = *(const float4*)(Ar + 12);
    float4 w0 = *(const float4*)(Wr    ), w1 = *(const float4*)(Wr + 4);
    float4 w2 = *(const float4*)(Wr + 8), w3 = *(const float4*)(Wr + 12);

    #pragma unroll 1
    for (int k0 = 32; k0 <= 768; k0 += 32) {
        // convert current tile in-register
        uint4 ah0, al0, ah1, al1, wh0, wl0, wh1, wl1;
        pack8(a0, a1, ah0, al0);  pack8(a2, a3, ah1, al1);
        pack8(w0, w1, wh0, wl0);  pack8(w2, w3, wh1, wl1);
        __syncthreads();                       // prev step's frag reads done
        *(uint4*)&Ah[wi0] = ah0;  *(uint4*)&Al[wi0] = al0;
        *(uint4*)&Ah[wi1] = ah1;  *(uint4*)&Al[wi1] = al1;
        *(uint4*)&Wh[wi0] = wh0;  *(uint4*)&Wl[wi0] = wl0;
        *(uint4*)&Wh[wi1] = wh1;  *(uint4*)&Wl[wi1] = wl1;
        __syncthreads();                       // stores visible
        if (k0 < 768) {                        // prefetch next (hides under MFMA)
            a0 = *(const float4*)(Ar + k0);     a1 = *(const float4*)(Ar + k0 + 4);
            a2 = *(const float4*)(Ar + k0 + 8); a3 = *(const float4*)(Ar + k0 + 12);
            w0 = *(const float4*)(Wr + k0);     w1 = *(const float4*)(Wr + k0 + 4);
            w2 = *(const float4*)(Wr + k0 + 8); w3 = *(const float4*)(Wr + k0 + 12);
        }
        bf16x8 fah[4], fal[4], fbh[4], fbl[4];
        #pragma unroll
        for (int i = 0; i < 4; ++i) {
            fah[i] = *(const bf16x8*)&Ah[aidx[i]];
            fal[i] = *(const bf16x8*)&Al[aidx[i]];
            fbh[i] = *(const bf16x8*)&Wh[bidx[i]];
            fbl[i] = *(const bf16x8*)&Wl[bidx[i]];
        }
        #pragma unroll
        for (int mi = 0; mi < 4; ++mi)
            #pragma unroll
            for (int ni = 0; ni < 4; ++ni) {
                acc[mi][ni] = __builtin_amdgcn_mfma_f32_16x16x32_bf16(fah[mi], fbh[ni], acc[mi][ni], 0, 0, 0);
                acc[mi][ni] = __builtin_amdgcn_mfma_f32_16x16x32_bf16(fah[mi], fbl[ni], acc[mi][ni], 0, 0, 0);
                acc[mi][ni] = __builtin_amdgcn_mfma_f32_16x16x32_bf16(fal[mi], fbh[ni], acc[mi][ni], 0, 0, 0);
            }
    }

    // epilogue: D element (reg r of lane) -> row = g*4 + r, col = fr  [m89]
    #pragma unroll
    for (int ni = 0; ni < 4; ++ni) {
        const int o16 = o0 + wn * 64 + ni * 16;           // uniform per wave
        const float bv = bias[o16 + fr];
        if (SCATTER) {
            const int sidx = o16 / 768;
            const int rem0 = o16 - sidx * 768;
            const int hh   = rem0 >> 6;
            const int dd   = (rem0 & 63) + fr;
            #pragma unroll
            for (int mi = 0; mi < 4; ++mi) {
                #pragma unroll
                for (int r = 0; r < 4; ++r) {
                    const int m = m0 + wm * 64 + mi * 16 + g * 4 + r;
                    const int token = m & 1023;
                    const int bh = (m >> 10) * 12 + hh;
                    const float val = acc[mi][ni][r] + bv;
                    if (sidx == 0)
                        C0[((size_t)bh * 1024 + token) * 64 + dd] = val * 0.125f;
                    else if (sidx == 1)
                        C1[(size_t)bh * 65536 + (size_t)dd * 1024 + token] = val;
                    else
                        C2[((size_t)bh * 1024 + token) * 64 + dd] = val;
                }
            }
        } else {
            #pragma unroll
            for (int mi = 0; mi < 4; ++mi) {
                #pragma unroll
                for (int r = 0; r < 4; ++r) {
                    const int m = m0 + wm * 64 + mi * 16 + g * 4 + r;
                    C0[(size_t)m * 768 + o16 + fr] = acc[mi][ni][r] + bv;
                }
            }
        }
    }
}

// ---------------------------------------------------------------------------
// Scores + softmax + row0 fix + attn write. 16 query rows per block.
// Phase 1 COALESCED via K^T[d][n]: each thread owns 4 CONSECUTIVE keys;
// one float4 load per d = fully-coalesced wave read. (round-7 code, passed)
// grid = (64 row-tiles, 48 bh), 256 threads, 68 KB LDS.
// ---------------------------------------------------------------------------
__global__ __launch_bounds__(256)
void attn_scores(const float* __restrict__ Q, const float* __restrict__ KT,
                 const float* __restrict__ cls_bias, float* __restrict__ attn)
{
    __shared__ float s[16 * 1024];   // 64 KB: 16 score rows
    __shared__ float qs[16 * 64];    // 4 KB: Q tile (pre-scaled by 0.125)
    const int tid = threadIdx.x;
    const int bh  = blockIdx.y;
    const int rt  = blockIdx.x;
    const int q0  = rt << 4;
    const size_t bhoff = (size_t)bh << 16;   // bh * 1024 * 64

    ((float4*)qs)[tid] = ((const float4*)(Q + bhoff + ((size_t)q0 << 6)))[tid];
    __syncthreads();

    // ---- phase 1: acc[q][j] = Q[q] . keys (4*tid+j), K^T coalesced ----
    {
        const float* KTb = KT + bhoff;       // [d][n]: d*1024 + n
        const int kb = tid << 2;             // 4 consecutive keys
        float acc[16][4] = {};
        float4 kf = *(const float4*)(KTb + kb);
        #pragma unroll 1
        for (int d = 0; d < 64; ++d) {
            const int dn = (d < 63) ? d + 1 : 63;            // clamped prefetch
            float4 kn = *(const float4*)(KTb + ((size_t)dn << 10) + kb);
            #pragma unroll
            for (int q = 0; q < 16; ++q) {
                const float qv = qs[(q << 6) + d];           // LDS broadcast
                acc[q][0] = fmaf(qv, kf.x, acc[q][0]);
                acc[q][1] = fmaf(qv, kf.y, acc[q][1]);
                acc[q][2] = fmaf(qv, kf.z, acc[q][2]);
                acc[q][3] = fmaf(qv, kf.w, acc[q][3]);
            }
            kf = kn;
        }
        #pragma unroll
        for (int q = 0; q < 16; ++q) {
            float4 r = {acc[q][0], acc[q][1], acc[q][2], acc[q][3]};
            *(float4*)&s[(q << 10) + kb] = r;
        }
    }
    __syncthreads();

    // ---- phase 2: softmax, 16 lanes per row; (j+q) rotation -> 2-way banks
    {
        const int q = tid >> 4, sub = tid & 15;
        float* row = s + (q << 10);
        float mx = -3.0e38f;
        #pragma unroll 4
        for (int j = 0; j < 64; ++j)
            mx = fmaxf(mx, row[sub + (((j + q) & 63) << 4)]);
        #pragma unroll
        for (int off = 8; off; off >>= 1) mx = fmaxf(mx, __shfl_xor(mx, off, 16));
        float sm = 0.f;
        #pragma unroll 4
        for (int j = 0; j < 64; ++j) {
            const int k = sub + (((j + q) & 63) << 4);
            const float e = __expf(row[k] - mx);
            row[k] = e;
            sm += e;
        }
        #pragma unroll
        for (int off = 8; off; off >>= 1) sm += __shfl_xor(sm, off, 16);
        const float inv = 1.0f / sm;
        #pragma unroll 4
        for (int j = 0; j < 64; ++j)
            row[sub + (((j + q) & 63) << 4)] *= inv;
    }

    // ---- row0 fix: global query 0 (lanes 0..15 of q-group 0, same wave) ----
    if (rt == 0 && tid < 16) {
        const float p0  = s[0];
        const float a00 = fminf(fmaxf(p0 + cls_bias[bh % 12], 0.f), 1.f);
        float actual = 0.f;
        for (int j = 0; j < 64; ++j) {
            const int k = tid + (j << 4);
            if (k) actual += s[k];
        }
        #pragma unroll
        for (int off = 8; off; off >>= 1) actual += __shfl_xor(actual, off, 16);
        const float mp = (1.0f - a00) / (actual + 1e-6f);
        for (int j = 0; j < 64; ++j) {
            const int k = tid + (j << 4);
            s[k] = (k == 0) ? a00 : fminf(fmaxf(s[k] * mp, 0.f), 1.f);
        }
    }
    __syncthreads();

    // ---- phase 3: write attn (output 1), coalesced float4 ----
    {
        float4* dst = (float4*)(attn + ((size_t)bh << 20) + ((size_t)q0 << 10));
        const float4* src = (const float4*)s;
        #pragma unroll
        for (int i = 0; i < 16; ++i)
            dst[tid + (i << 8)] = src[tid + (i << 8)];
    }
}

// ---------------------------------------------------------------------------
// O1 = attn @ V per (b,h): M=1024, K=1024, N=64. Tiled GEMM, 64x64 tile,
// Bk=16, 4x4 micro-tile, double-buffered LDS. (round-7 code, passed)
// grid = (16 m-tiles, 48 bh), 256 threads, ~17 KB LDS.
// ---------------------------------------------------------------------------
__global__ __launch_bounds__(256)
void pv_gemm(const float* __restrict__ attn, const float* __restrict__ V,
             float* __restrict__ O1)
{
    __shared__ float Pt[2][16][68];   // [buf][k][m], stride 272 B
    __shared__ float Vt[2][16][64];   // [buf][k][n]
    const int tid = threadIdx.x;
    const int bh  = blockIdx.y;
    const int m0  = blockIdx.x << 6;
    const int b   = bh / 12, h = bh - b * 12;
    const size_t bhoff = (size_t)bh << 16;
    const float* Pg = attn + ((size_t)bh << 20);

    const int pr = tid >> 2;            // 0..63  P stage row
    const int pk = (tid & 3) << 2;      // 0,4,8,12
    const int vk = tid >> 4;            // 0..15  V stage k
    const int vn = (tid & 15) << 2;     // n quad
    const int tx = tid & 15, ty = tid >> 4;

    // prologue: stage k0=0 into buffer 0
    {
        float4 pv4 = *(const float4*)(Pg + (size_t)(m0 + pr) * 1024 + pk);
        float4 vv4 = *(const float4*)(V + bhoff + (size_t)vk * 64 + vn);
        Pt[0][pk+0][pr] = pv4.x; Pt[0][pk+1][pr] = pv4.y;
        Pt[0][pk+2][pr] = pv4.z; Pt[0][pk+3][pr] = pv4.w;
        *(float4*)&Vt[0][vk][vn] = vv4;
    }
    __syncthreads();

    float acc[4][4] = {};
    int cur = 0;

    for (int k0 = 16; k0 <= 1024; k0 += 16) {
        const bool more = (k0 < 1024);
        float4 pv4, vv4;
        if (more) {
            pv4 = *(const float4*)(Pg + (size_t)(m0 + pr) * 1024 + k0 + pk);
            vv4 = *(const float4*)(V + bhoff + (size_t)(k0 + vk) * 64 + vn);
        }
        #pragma unroll
        for (int kk = 0; kk < 16; ++kk) {
            float4 a  = *(const float4*)&Pt[cur][kk][ty << 2];
            float4 bv = *(const float4*)&Vt[cur][kk][tx << 2];
            float av[4] = {a.x, a.y, a.z, a.w};
            float bb[4] = {bv.x, bv.y, bv.z, bv.w};
            #pragma unroll
            for (int i = 0; i < 4; ++i)
                #pragma unroll
                for (int j = 0; j < 4; ++j)
                    acc[i][j] = fmaf(av[i], bb[j], acc[i][j]);
        }
        if (more) {
            __syncthreads();
            const int nb = cur ^ 1;
            Pt[nb][pk+0][pr] = pv4.x; Pt[nb][pk+1][pr] = pv4.y;
            Pt[nb][pk+2][pr] = pv4.z; Pt[nb][pk+3][pr] = pv4.w;
            *(float4*)&Vt[nb][vk][vn] = vv4;
            __syncthreads();
            cur = nb;
        }
    }

    #pragma unroll
    for (int i = 0; i < 4; ++i) {
        float4 r = {acc[i][0], acc[i][1], acc[i][2], acc[i][3]};
        const int m = m0 + (ty << 2) + i;
        *(float4*)(O1 + ((size_t)(b * 1024 + m)) * 768 + (h << 6) + (tx << 2)) = r;
    }
}

extern "C" void kernel_launch(void* const* d_in, const int* in_sizes, int n_in,
                              void* d_out, int out_size, void* d_ws, size_t ws_size,
                              hipStream_t stream) {
    const float* x        = (const float*)d_in[0];
    const float* qkv_w    = (const float*)d_in[1];
    const float* qkv_b    = (const float*)d_in[2];
    const float* proj_w   = (const float*)d_in[3];
    const float* proj_b   = (const float*)d_in[4];
    const float* cls_bias = (const float*)d_in[5];

    float* out  = (float*)d_out;
    float* attn = out + OUT0_ELEMS;

    float* ws = (float*)d_ws;
    float* Q  = ws;                       // 12.6 MB (pre-scaled by 0.125), [bh][n][d]
    float* KT = Q  + (size_t)QKV_F32;     // 12.6 MB, [bh][d][n]  (transposed)
    float* V  = KT + (size_t)QKV_F32;     // 12.6 MB, [bh][n][d]
    float* O1 = V  + (size_t)QKV_F32;     // 12.6 MB

    // 1) qkv = x @ qkv_w.T + qkv_b -> Q(scaled)/KT/V   (bf16-split MFMA)
    gemm_mfma<1><<<dim3(18, 32), 256, 0, stream>>>(x, qkv_w, qkv_b, Q, KT, V);
    // 2) attn = row0-fixed softmax(Q K^T)  (output 1)
    attn_scores<<<dim3(64, 48), 256, 0, stream>>>(Q, KT, cls_bias, attn);
    // 3) O1 = attn @ V
    pv_gemm<<<dim3(16, 48), 256, 0, stream>>>(attn, V, O1);
    // 4) out = O1 @ proj_w.T + proj_b  (output 0, bf16-split MFMA)
    gemm_mfma<0><<<dim3(6, 32), 256, 0, stream>>>(O1, proj_w, proj_b, out, nullptr, nullptr);
}

// Round 9
// 607.025 us; speedup vs baseline: 1.6670x; 1.1143x over previous
//
#include <hip/hip_runtime.h>
#include <cstdint>

// Problem: B=4, N=1024, C=768, H=12, hd=64
// Outputs fp32 concat: out[4,1024,768] then attn[4,12,1024,1024]
#define OUT0_ELEMS 3145728   // 4096*768
#define QKV_F32    3145728   // 48*1024*64 elements per tensor

typedef __attribute__((ext_vector_type(8))) short bf16x8;   // 8 bf16 = 4 VGPR
typedef __attribute__((ext_vector_type(4))) float f32x4;    // MFMA C/D

// Truncating bf16 split: x ~= h + l with |x - h - l| <= 2^-16 |x|.
__device__ __forceinline__ void split_bf16(float x, unsigned short &h, unsigned short &l) {
    unsigned bx = __float_as_uint(x);
    h = (unsigned short)(bx >> 16);
    float fh = __uint_as_float(((unsigned)h) << 16);
    float r  = x - fh;
    l = (unsigned short)(__float_as_uint(r) >> 16);
}

// 8 consecutive floats (two float4) -> packed hi-chunk + lo-chunk (8 bf16 each).
__device__ __forceinline__ void pack8(const float4 &u, const float4 &v,
                                      uint4 &hp, uint4 &lp) {
    unsigned short h0,l0,h1,l1,h2,l2,h3,l3,h4,l4,h5,l5,h6,l6,h7,l7;
    split_bf16(u.x,h0,l0); split_bf16(u.y,h1,l1);
    split_bf16(u.z,h2,l2); split_bf16(u.w,h3,l3);
    split_bf16(v.x,h4,l4); split_bf16(v.y,h5,l5);
    split_bf16(v.z,h6,l6); split_bf16(v.w,h7,l7);
    hp = make_uint4((unsigned)h0 | ((unsigned)h1 << 16), (unsigned)h2 | ((unsigned)h3 << 16),
                    (unsigned)h4 | ((unsigned)h5 << 16), (unsigned)h6 | ((unsigned)h7 << 16));
    lp = make_uint4((unsigned)l0 | ((unsigned)l1 << 16), (unsigned)l2 | ((unsigned)l3 << 16),
                    (unsigned)l4 | ((unsigned)l5 << 16), (unsigned)l6 | ((unsigned)l7 << 16));
}

// ---------------------------------------------------------------------------
// MFMA GEMM via bf16 split: C[M][O] = A[M][768] @ W[O][768]^T + bias.
// BM=BN=128, BK=32, 256 threads = 4 waves (2x2), each wave 64x64 output
// = 4x4 mfma_f32_16x16x32_bf16 frags; 3 passes (hh, hl, lh) per k-step.
// (round-8 code, passed)
// ---------------------------------------------------------------------------
template<int SCATTER>
__global__ __launch_bounds__(256)
void gemm_mfma(const float* __restrict__ A, const float* __restrict__ W,
               const float* __restrict__ bias,
               float* __restrict__ C0, float* __restrict__ C1, float* __restrict__ C2)
{
    __shared__ __align__(16) unsigned short Ah[4096], Al[4096], Wh[4096], Wl[4096];
    const int tid = threadIdx.x;
    const int m0 = blockIdx.y * 128;
    const int o0 = blockIdx.x * 128;

    // staging: thread -> (row, k-half); two 8-bf16 chunks per tile
    const int srow  = tid >> 1;
    const int khalf = tid & 1;
    const int sswz  = (srow >> 1) & 3;
    const int wi0 = srow * 32 + (((khalf << 1)    ) ^ sswz) * 8;
    const int wi1 = srow * 32 + (((khalf << 1) | 1) ^ sswz) * 8;

    const float* Ar = A + (size_t)(m0 + srow) * 768 + khalf * 16;
    const float* Wr = W + (size_t)(o0 + srow) * 768 + khalf * 16;

    // wave/lane decomposition for MFMA fragments
    const int l   = tid & 63;
    const int wid = tid >> 6;
    const int wm  = wid >> 1, wn = wid & 1;
    const int fr  = l & 15;          // A-row / B-col within frag
    const int g   = l >> 4;          // k-chunk (8 bf16)
    int aidx[4], bidx[4];
    #pragma unroll
    for (int i = 0; i < 4; ++i) {
        const int ar = wm * 64 + i * 16 + fr;
        aidx[i] = ar * 32 + ((g ^ ((ar >> 1) & 3)) * 8);
        const int br = wn * 64 + i * 16 + fr;
        bidx[i] = br * 32 + ((g ^ ((br >> 1) & 3)) * 8);
    }

    const f32x4 zf = {0.f, 0.f, 0.f, 0.f};
    f32x4 acc[4][4];
    #pragma unroll
    for (int i = 0; i < 4; ++i)
        #pragma unroll
        for (int j = 0; j < 4; ++j) acc[i][j] = zf;

    // prologue: load k-step 0
    float4 a0 = *(const float4*)(Ar    ), a1 = *(const float4*)(Ar + 4);
    float4 a2 = *(const float4*)(Ar + 8), a3 = *(const float4*)(Ar + 12);
    float4 w0 = *(const float4*)(Wr    ), w1 = *(const float4*)(Wr + 4);
    float4 w2 = *(const float4*)(Wr + 8), w3 = *(const float4*)(Wr + 12);

    #pragma unroll 1
    for (int k0 = 32; k0 <= 768; k0 += 32) {
        // convert current tile in-register
        uint4 ah0, al0, ah1, al1, wh0, wl0, wh1, wl1;
        pack8(a0, a1, ah0, al0);  pack8(a2, a3, ah1, al1);
        pack8(w0, w1, wh0, wl0);  pack8(w2, w3, wh1, wl1);
        __syncthreads();                       // prev step's frag reads done
        *(uint4*)&Ah[wi0] = ah0;  *(uint4*)&Al[wi0] = al0;
        *(uint4*)&Ah[wi1] = ah1;  *(uint4*)&Al[wi1] = al1;
        *(uint4*)&Wh[wi0] = wh0;  *(uint4*)&Wl[wi0] = wl0;
        *(uint4*)&Wh[wi1] = wh1;  *(uint4*)&Wl[wi1] = wl1;
        __syncthreads();                       // stores visible
        if (k0 < 768) {                        // prefetch next (hides under MFMA)
            a0 = *(const float4*)(Ar + k0);     a1 = *(const float4*)(Ar + k0 + 4);
            a2 = *(const float4*)(Ar + k0 + 8); a3 = *(const float4*)(Ar + k0 + 12);
            w0 = *(const float4*)(Wr + k0);     w1 = *(const float4*)(Wr + k0 + 4);
            w2 = *(const float4*)(Wr + k0 + 8); w3 = *(const float4*)(Wr + k0 + 12);
        }
        bf16x8 fah[4], fal[4], fbh[4], fbl[4];
        #pragma unroll
        for (int i = 0; i < 4; ++i) {
            fah[i] = *(const bf16x8*)&Ah[aidx[i]];
            fal[i] = *(const bf16x8*)&Al[aidx[i]];
            fbh[i] = *(const bf16x8*)&Wh[bidx[i]];
            fbl[i] = *(const bf16x8*)&Wl[bidx[i]];
        }
        #pragma unroll
        for (int mi = 0; mi < 4; ++mi)
            #pragma unroll
            for (int ni = 0; ni < 4; ++ni) {
                acc[mi][ni] = __builtin_amdgcn_mfma_f32_16x16x32_bf16(fah[mi], fbh[ni], acc[mi][ni], 0, 0, 0);
                acc[mi][ni] = __builtin_amdgcn_mfma_f32_16x16x32_bf16(fah[mi], fbl[ni], acc[mi][ni], 0, 0, 0);
                acc[mi][ni] = __builtin_amdgcn_mfma_f32_16x16x32_bf16(fal[mi], fbh[ni], acc[mi][ni], 0, 0, 0);
            }
    }

    // epilogue: D element (reg r of lane) -> row = g*4 + r, col = fr  [m89]
    #pragma unroll
    for (int ni = 0; ni < 4; ++ni) {
        const int o16 = o0 + wn * 64 + ni * 16;           // uniform per wave
        const float bv = bias[o16 + fr];
        if (SCATTER) {
            const int sidx = o16 / 768;
            const int rem0 = o16 - sidx * 768;
            const int hh   = rem0 >> 6;
            const int dd   = (rem0 & 63) + fr;
            #pragma unroll
            for (int mi = 0; mi < 4; ++mi) {
                #pragma unroll
                for (int r = 0; r < 4; ++r) {
                    const int m = m0 + wm * 64 + mi * 16 + g * 4 + r;
                    const int token = m & 1023;
                    const int bh = (m >> 10) * 12 + hh;
                    const float val = acc[mi][ni][r] + bv;
                    if (sidx == 0)
                        C0[((size_t)bh * 1024 + token) * 64 + dd] = val * 0.125f;
                    else if (sidx == 1)
                        C1[(size_t)bh * 65536 + (size_t)dd * 1024 + token] = val;
                    else
                        C2[((size_t)bh * 1024 + token) * 64 + dd] = val;
                }
            }
        } else {
            #pragma unroll
            for (int mi = 0; mi < 4; ++mi) {
                #pragma unroll
                for (int r = 0; r < 4; ++r) {
                    const int m = m0 + wm * 64 + mi * 16 + g * 4 + r;
                    C0[(size_t)m * 768 + o16 + fr] = acc[mi][ni][r] + bv;
                }
            }
        }
    }
}

// ---------------------------------------------------------------------------
// Scores + softmax + row0 fix + attn write. 16 query rows per block.
// Phase 1 COALESCED via K^T[d][n] with a DEPTH-4 prefetch ring: each kbuf
// slot is reloaded 4 d-iterations (~512 FMA cyc) before reuse, covering the
// ~200-400 cyc L2 latency that made the depth-1 version stall (round-8 PMC:
// 234 us at VALUBusy 40% with ~35 us of issue demand = latency-bound).
// Phases 2-4 are the round-8 code verbatim (passed).
// grid = (64 row-tiles, 48 bh), 256 threads, 68 KB LDS.
// ---------------------------------------------------------------------------
__global__ __launch_bounds__(256)
void attn_scores(const float* __restrict__ Q, const float* __restrict__ KT,
                 const float* __restrict__ cls_bias, float* __restrict__ attn)
{
    __shared__ float s[16 * 1024];   // 64 KB: 16 score rows
    __shared__ float qs[16 * 64];    // 4 KB: Q tile (pre-scaled by 0.125)
    const int tid = threadIdx.x;
    const int bh  = blockIdx.y;
    const int rt  = blockIdx.x;
    const int q0  = rt << 4;
    const size_t bhoff = (size_t)bh << 16;   // bh * 1024 * 64

    ((float4*)qs)[tid] = ((const float4*)(Q + bhoff + ((size_t)q0 << 6)))[tid];
    __syncthreads();

    // ---- phase 1: acc[q][j] = Q[q] . keys (4*tid+j), K^T coalesced ----
    {
        const float* KTb = KT + bhoff;       // [d][n]: d*1024 + n
        const int kb = tid << 2;             // 4 consecutive keys
        float acc[16][4] = {};
        float4 kbuf[4];                      // depth-4 ring, statically indexed
        #pragma unroll
        for (int j = 0; j < 4; ++j)
            kbuf[j] = *(const float4*)(KTb + ((size_t)j << 10) + kb);

        #pragma unroll 1
        for (int d4 = 0; d4 < 64; d4 += 4) {
            #pragma unroll
            for (int j = 0; j < 4; ++j) {
                const int d  = d4 + j;
                const float4 kf = kbuf[j];
                const int dn = d + 4;
                if (dn < 64)                 // reload slot 4 iters ahead
                    kbuf[j] = *(const float4*)(KTb + ((size_t)dn << 10) + kb);
                #pragma unroll
                for (int q = 0; q < 16; ++q) {
                    const float qv = qs[(q << 6) + d];       // LDS broadcast
                    acc[q][0] = fmaf(qv, kf.x, acc[q][0]);
                    acc[q][1] = fmaf(qv, kf.y, acc[q][1]);
                    acc[q][2] = fmaf(qv, kf.z, acc[q][2]);
                    acc[q][3] = fmaf(qv, kf.w, acc[q][3]);
                }
            }
        }
        #pragma unroll
        for (int q = 0; q < 16; ++q) {
            float4 r = {acc[q][0], acc[q][1], acc[q][2], acc[q][3]};
            *(float4*)&s[(q << 10) + kb] = r;
        }
    }
    __syncthreads();

    // ---- phase 2: softmax, 16 lanes per row; (j+q) rotation -> 2-way banks
    {
        const int q = tid >> 4, sub = tid & 15;
        float* row = s + (q << 10);
        float mx = -3.0e38f;
        #pragma unroll 4
        for (int j = 0; j < 64; ++j)
            mx = fmaxf(mx, row[sub + (((j + q) & 63) << 4)]);
        #pragma unroll
        for (int off = 8; off; off >>= 1) mx = fmaxf(mx, __shfl_xor(mx, off, 16));
        float sm = 0.f;
        #pragma unroll 4
        for (int j = 0; j < 64; ++j) {
            const int k = sub + (((j + q) & 63) << 4);
            const float e = __expf(row[k] - mx);
            row[k] = e;
            sm += e;
        }
        #pragma unroll
        for (int off = 8; off; off >>= 1) sm += __shfl_xor(sm, off, 16);
        const float inv = 1.0f / sm;
        #pragma unroll 4
        for (int j = 0; j < 64; ++j)
            row[sub + (((j + q) & 63) << 4)] *= inv;
    }

    // ---- row0 fix: global query 0 (lanes 0..15 of q-group 0, same wave) ----
    if (rt == 0 && tid < 16) {
        const float p0  = s[0];
        const float a00 = fminf(fmaxf(p0 + cls_bias[bh % 12], 0.f), 1.f);
        float actual = 0.f;
        for (int j = 0; j < 64; ++j) {
            const int k = tid + (j << 4);
            if (k) actual += s[k];
        }
        #pragma unroll
        for (int off = 8; off; off >>= 1) actual += __shfl_xor(actual, off, 16);
        const float mp = (1.0f - a00) / (actual + 1e-6f);
        for (int j = 0; j < 64; ++j) {
            const int k = tid + (j << 4);
            s[k] = (k == 0) ? a00 : fminf(fmaxf(s[k] * mp, 0.f), 1.f);
        }
    }
    __syncthreads();

    // ---- phase 3: write attn (output 1), coalesced float4 ----
    {
        float4* dst = (float4*)(attn + ((size_t)bh << 20) + ((size_t)q0 << 10));
        const float4* src = (const float4*)s;
        #pragma unroll
        for (int i = 0; i < 16; ++i)
            dst[tid + (i << 8)] = src[tid + (i << 8)];
    }
}

// ---------------------------------------------------------------------------
// O1 = attn @ V per (b,h): M=1024, K=1024, N=64. Tiled GEMM, 64x64 tile,
// Bk=16, 4x4 micro-tile, double-buffered LDS. (round-8 code, passed)
// grid = (16 m-tiles, 48 bh), 256 threads, ~17 KB LDS.
// ---------------------------------------------------------------------------
__global__ __launch_bounds__(256)
void pv_gemm(const float* __restrict__ attn, const float* __restrict__ V,
             float* __restrict__ O1)
{
    __shared__ float Pt[2][16][68];   // [buf][k][m], stride 272 B
    __shared__ float Vt[2][16][64];   // [buf][k][n]
    const int tid = threadIdx.x;
    const int bh  = blockIdx.y;
    const int m0  = blockIdx.x << 6;
    const int b   = bh / 12, h = bh - b * 12;
    const size_t bhoff = (size_t)bh << 16;
    const float* Pg = attn + ((size_t)bh << 20);

    const int pr = tid >> 2;            // 0..63  P stage row
    const int pk = (tid & 3) << 2;      // 0,4,8,12
    const int vk = tid >> 4;            // 0..15  V stage k
    const int vn = (tid & 15) << 2;     // n quad
    const int tx = tid & 15, ty = tid >> 4;

    // prologue: stage k0=0 into buffer 0
    {
        float4 pv4 = *(const float4*)(Pg + (size_t)(m0 + pr) * 1024 + pk);
        float4 vv4 = *(const float4*)(V + bhoff + (size_t)vk * 64 + vn);
        Pt[0][pk+0][pr] = pv4.x; Pt[0][pk+1][pr] = pv4.y;
        Pt[0][pk+2][pr] = pv4.z; Pt[0][pk+3][pr] = pv4.w;
        *(float4*)&Vt[0][vk][vn] = vv4;
    }
    __syncthreads();

    float acc[4][4] = {};
    int cur = 0;

    for (int k0 = 16; k0 <= 1024; k0 += 16) {
        const bool more = (k0 < 1024);
        float4 pv4, vv4;
        if (more) {
            pv4 = *(const float4*)(Pg + (size_t)(m0 + pr) * 1024 + k0 + pk);
            vv4 = *(const float4*)(V + bhoff + (size_t)(k0 + vk) * 64 + vn);
        }
        #pragma unroll
        for (int kk = 0; kk < 16; ++kk) {
            float4 a  = *(const float4*)&Pt[cur][kk][ty << 2];
            float4 bv = *(const float4*)&Vt[cur][kk][tx << 2];
            float av[4] = {a.x, a.y, a.z, a.w};
            float bb[4] = {bv.x, bv.y, bv.z, bv.w};
            #pragma unroll
            for (int i = 0; i < 4; ++i)
                #pragma unroll
                for (int j = 0; j < 4; ++j)
                    acc[i][j] = fmaf(av[i], bb[j], acc[i][j]);
        }
        if (more) {
            __syncthreads();
            const int nb = cur ^ 1;
            Pt[nb][pk+0][pr] = pv4.x; Pt[nb][pk+1][pr] = pv4.y;
            Pt[nb][pk+2][pr] = pv4.z; Pt[nb][pk+3][pr] = pv4.w;
            *(float4*)&Vt[nb][vk][vn] = vv4;
            __syncthreads();
            cur = nb;
        }
    }

    #pragma unroll
    for (int i = 0; i < 4; ++i) {
        float4 r = {acc[i][0], acc[i][1], acc[i][2], acc[i][3]};
        const int m = m0 + (ty << 2) + i;
        *(float4*)(O1 + ((size_t)(b * 1024 + m)) * 768 + (h << 6) + (tx << 2)) = r;
    }
}

extern "C" void kernel_launch(void* const* d_in, const int* in_sizes, int n_in,
                              void* d_out, int out_size, void* d_ws, size_t ws_size,
                              hipStream_t stream) {
    const float* x        = (const float*)d_in[0];
    const float* qkv_w    = (const float*)d_in[1];
    const float* qkv_b    = (const float*)d_in[2];
    const float* proj_w   = (const float*)d_in[3];
    const float* proj_b   = (const float*)d_in[4];
    const float* cls_bias = (const float*)d_in[5];

    float* out  = (float*)d_out;
    float* attn = out + OUT0_ELEMS;

    float* ws = (float*)d_ws;
    float* Q  = ws;                       // 12.6 MB (pre-scaled by 0.125), [bh][n][d]
    float* KT = Q  + (size_t)QKV_F32;     // 12.6 MB, [bh][d][n]  (transposed)
    float* V  = KT + (size_t)QKV_F32;     // 12.6 MB, [bh][n][d]
    float* O1 = V  + (size_t)QKV_F32;     // 12.6 MB

    // 1) qkv = x @ qkv_w.T + qkv_b -> Q(scaled)/KT/V   (bf16-split MFMA)
    gemm_mfma<1><<<dim3(18, 32), 256, 0, stream>>>(x, qkv_w, qkv_b, Q, KT, V);
    // 2) attn = row0-fixed softmax(Q K^T)  (output 1)
    attn_scores<<<dim3(64, 48), 256, 0, stream>>>(Q, KT, cls_bias, attn);
    // 3) O1 = attn @ V
    pv_gemm<<<dim3(16, 48), 256, 0, stream>>>(attn, V, O1);
    // 4) out = O1 @ proj_w.T + proj_b  (output 0, bf16-split MFMA)
    gemm_mfma<0><<<dim3(6, 32), 256, 0, stream>>>(O1, proj_w, proj_b, out, nullptr, nullptr);
}